// Round 3
// baseline (507.946 us; speedup 1.0000x reference)
//
#include <hip/hip_runtime.h>
#include <hip/hip_fp16.h>
#include <cstdint>
#include <cstddef>

#define M_DIM 8192
#define N_DIM 4096
#define K_DIM 4096

typedef int v4i __attribute__((ext_vector_type(4)));

// ---------------------------------------------------------------------------
// Pack kernel: int32 (harness-widened int8) -> int8.
// 16B coalesced load -> 4B coalesced store per thread.
// ---------------------------------------------------------------------------
__global__ __launch_bounds__(256) void pack_i32_to_i8(const int* __restrict__ src,
                                                      uint32_t* __restrict__ dst,
                                                      int n4) {
    int i = blockIdx.x * 256 + threadIdx.x;
    if (i >= n4) return;
    int4 a = ((const int4*)src)[i];
#if __has_builtin(__builtin_amdgcn_perm)
    // v_perm_b32: select byte0 of each of the four int32s
    uint32_t lo = __builtin_amdgcn_perm((uint32_t)a.y, (uint32_t)a.x, 0x0400);
    uint32_t hi = __builtin_amdgcn_perm((uint32_t)a.w, (uint32_t)a.z, 0x0400);
    dst[i] = __builtin_amdgcn_perm(hi, lo, 0x05040100);
#else
    dst[i] = (uint32_t)(a.x & 0xff) | ((uint32_t)(a.y & 0xff) << 8) |
             ((uint32_t)(a.z & 0xff) << 16) | ((uint32_t)a.w << 24);
#endif
}

// ---------------------------------------------------------------------------
// async global->LDS, 16B per lane (global_load_lds_dwordx4)
// ---------------------------------------------------------------------------
__device__ __forceinline__ void gload_lds16(const int8_t* g, int8_t* l) {
    __builtin_amdgcn_global_load_lds(
        (const __attribute__((address_space(1))) void*)g,
        (__attribute__((address_space(3))) void*)l, 16, 0, 0);
}

// ---------------------------------------------------------------------------
// GEMM: C[m][n] = sum_k A[m][k]*W[n][k], int32 acc, fused dequant epilogue.
// 128x128 block tile, BK=64 (16 KB LDS -> high co-residency; BK=128 regressed
// to 271us via the occupancy cliff), 4 waves (2x2), wave tile 64x64 via 4x4
// MFMA tiles of mfma_i32_16x16x64_i8.
//
// LDS is FRAGMENT-ORDERED: sX[subtile s(8)][slot l(64)][16B]; subtile s holds
// rows s*16+(l&15), k-chunk (l>>4)*16. Staging lane l fetches exactly the 16B
// fragment lane l consumes -> ds_read_b128 reads are stride-1, zero bank
// conflicts (round 2: SQ_LDS_BANK_CONFLICT == 0), and global_load_lds's
// wave-uniform-base + l*16 constraint holds. Global staging still covers
// whole 64B lines (16 rows x 4 chunks per instruction).
//
// XCD patch swizzle: linear block id % 8 ~ XCD (dispatch heuristic); give
// each XCD a compact 8-bn x 32-bm patch so its rolling resident window
// (~32 blocks = 8bn x 4bm) has a ~96 KB/K-tile working set -> L2-resident,
// shorter vmcnt drain at the staging barrier.
// ---------------------------------------------------------------------------
__global__ __launch_bounds__(256) void gemm_i8_dq(const int8_t* __restrict__ A,
                                                  const int8_t* __restrict__ W,
                                                  const float* __restrict__ sx,
                                                  const float* __restrict__ sw,
                                                  const float* __restrict__ bias,
                                                  float* __restrict__ out) {
    __shared__ int8_t sA[128 * 64];   // 8 KB
    __shared__ int8_t sB[128 * 64];   // 8 KB

    const int t    = threadIdx.x;
    const int lane = t & 63;
    const int w    = t >> 6;          // wave 0..3
    const int wm   = w >> 1;          // 0..1
    const int wn   = w & 1;           // 0..1

    // XCD-patch swizzle (bijective remap of 2048 block ids)
    const int flat = blockIdx.y * 32 + blockIdx.x;
    const int xcd  = flat & 7;
    const int idx  = flat >> 3;                    // 0..255
    const int bn   = (xcd & 3) * 8 + (idx & 7);    // 0..31
    const int bm   = (xcd >> 2) * 32 + (idx >> 3); // 0..63

    const int r16  = lane & 15;       // row within 16-row subtile
    const int c16  = lane >> 4;       // 16B k-chunk

    // ---- staging addresses: 4 issues/thread per K-tile (2 A + 2 B) ----
    const int8_t* gA[2]; const int8_t* gB[2];
    int8_t* lA[2]; int8_t* lB[2];
#pragma unroll
    for (int j = 0; j < 2; j++) {
        const int s = j * 4 + w;      // subtile 0..7
        gA[j] = A + (size_t)(bm * 128 + s * 16 + r16) * K_DIM + c16 * 16;
        gB[j] = W + (size_t)(bn * 128 + s * 16 + r16) * K_DIM + c16 * 16;
        lA[j] = &sA[s * 1024 + lane * 16];
        lB[j] = &sB[s * 1024 + lane * 16];
    }

    v4i acc[4][4];
    const v4i vzero = {0, 0, 0, 0};
#pragma unroll
    for (int mi = 0; mi < 4; mi++)
#pragma unroll
        for (int ni = 0; ni < 4; ni++) acc[mi][ni] = vzero;

    for (int kt = 0; kt < K_DIM; kt += 64) {
        __syncthreads();              // previous tile's ds_reads done
#pragma unroll
        for (int j = 0; j < 2; j++) {
            gload_lds16(gA[j] + kt, lA[j]);
            gload_lds16(gB[j] + kt, lB[j]);
        }
        __syncthreads();              // staging complete

        v4i af[4], bf[4];
#pragma unroll
        for (int i = 0; i < 4; i++) {
            af[i] = *(const v4i*)(&sA[(wm * 4 + i) * 1024 + lane * 16]);
            bf[i] = *(const v4i*)(&sB[(wn * 4 + i) * 1024 + lane * 16]);
        }
#pragma unroll
        for (int mi = 0; mi < 4; mi++)
#pragma unroll
            for (int ni = 0; ni < 4; ni++)
                acc[mi][ni] = __builtin_amdgcn_mfma_i32_16x16x64_i8(
                    af[mi], bf[ni], acc[mi][ni], 0, 0, 0);
    }

    // ---- epilogue: C/D 16x16 layout: col = lane&15, row = (lane>>4)*4 + r ----
    const float DIVF = (float)(1.0 / (127.0 * 127.0));
    const int col0 = bn * 128 + wn * 64 + (lane & 15);
    const int row0 = bm * 128 + wm * 64 + (lane >> 4) * 4;

    float swv[4], bv[4];
#pragma unroll
    for (int ni = 0; ni < 4; ni++) {
        swv[ni] = sw[col0 + ni * 16];
        bv[ni]  = bias[col0 + ni * 16];
    }

#pragma unroll
    for (int mi = 0; mi < 4; mi++) {
#pragma unroll
        for (int r = 0; r < 4; r++) {
            const int row = row0 + mi * 16 + r;
            const float xs = sx[row];
#pragma unroll
            for (int ni = 0; ni < 4; ni++) {
                // numpy op order: ((acc_f * DIV) * sx) * sw + bias, no fma
                float v = __fmul_rn((float)acc[mi][ni][r], DIVF);
                v = __fmul_rn(v, xs);
                v = __fmul_rn(v, swv[ni]);
                v = __fadd_rn(v, bv[ni]);
                out[(size_t)row * N_DIM + col0 + ni * 16] = __half2float(__float2half(v));
            }
        }
    }
}

extern "C" void kernel_launch(void* const* d_in, const int* in_sizes, int n_in,
                              void* d_out, int out_size, void* d_ws, size_t ws_size,
                              hipStream_t stream) {
    const int*   x_i32 = (const int*)d_in[0];      // [M,K] int (widened int8)
    const float* sx    = (const float*)d_in[1];    // [M] f32
    const int*   w_i32 = (const int*)d_in[2];      // [N,K] int (widened int8)
    const float* sw    = (const float*)d_in[3];    // [N] f32
    const float* bias  = (const float*)d_in[4];    // [N] f32 (widened fp16)
    float* out = (float*)d_out;                    // [M,N] f32 (widened fp16)

    uint8_t* xb = (uint8_t*)d_ws;                          // 32 MB packed x
    uint8_t* wb = (uint8_t*)d_ws + (size_t)M_DIM * K_DIM;  // 16 MB packed w

    const int nx4 = (M_DIM * K_DIM) / 4;  // 8,388,608
    const int nw4 = (N_DIM * K_DIM) / 4;  // 4,194,304
    pack_i32_to_i8<<<(nx4 + 255) / 256, 256, 0, stream>>>(x_i32, (uint32_t*)xb, nx4);
    pack_i32_to_i8<<<(nw4 + 255) / 256, 256, 0, stream>>>(w_i32, (uint32_t*)wb, nw4);

    dim3 grid(N_DIM / 128, M_DIM / 128);  // (32, 64)
    gemm_i8_dq<<<grid, 256, 0, stream>>>((const int8_t*)xb, (const int8_t*)wb,
                                         sx, sw, bias, out);
}

// Round 4
// 415.135 us; speedup vs baseline: 1.2236x; 1.2236x over previous
//
#include <hip/hip_runtime.h>
#include <hip/hip_fp16.h>
#include <cstdint>
#include <cstddef>

#define M_DIM 8192
#define N_DIM 4096
#define K_DIM 4096

typedef int v4i __attribute__((ext_vector_type(4)));

// ---------------------------------------------------------------------------
// Pack kernel: int32 (harness-widened int8) -> int8.
// 16B coalesced load -> 4B coalesced store per thread; v_perm byte-select.
// ---------------------------------------------------------------------------
__global__ __launch_bounds__(256) void pack_i32_to_i8(const int* __restrict__ src,
                                                      uint32_t* __restrict__ dst,
                                                      int n4) {
    int i = blockIdx.x * 256 + threadIdx.x;
    if (i >= n4) return;
    int4 a = ((const int4*)src)[i];
#if __has_builtin(__builtin_amdgcn_perm)
    uint32_t lo = __builtin_amdgcn_perm((uint32_t)a.y, (uint32_t)a.x, 0x0400);
    uint32_t hi = __builtin_amdgcn_perm((uint32_t)a.w, (uint32_t)a.z, 0x0400);
    dst[i] = __builtin_amdgcn_perm(hi, lo, 0x05040100);
#else
    dst[i] = (uint32_t)(a.x & 0xff) | ((uint32_t)(a.y & 0xff) << 8) |
             ((uint32_t)(a.z & 0xff) << 16) | ((uint32_t)a.w << 24);
#endif
}

__device__ __forceinline__ void gload_lds16(const int8_t* g, int8_t* l) {
    __builtin_amdgcn_global_load_lds(
        (const __attribute__((address_space(1))) void*)g,
        (__attribute__((address_space(3))) void*)l, 16, 0, 0);
}

// ---------------------------------------------------------------------------
// GEMM: C[m][n] = sum_k A[m][k]*W[n][k], int32 acc, fused dequant epilogue.
// 128x128 tile, BK=64 (16 KB LDS), 4 waves (2x2), wave tile 64x64 via 4x4
// mfma_i32_16x16x64_i8.
//
// Staging (round-1 map, coalesced at quad granularity): thread t covers
// row srow=t>>2, physical 16B slot p=t&3; the 4 lanes of each quad cover one
// contiguous 64B row-segment. LDS dst = t*16 (wave-uniform base + lane*16).
// [Round 2/3's fragment-ordered map scattered each 64B segment across lanes
//  {r,r+16,r+32,r+48} -> 4x VMEM transactions -> +95us stall. Reverted.]
//
// CHUNK-ROTATION SWIZZLE (kills round 1's 4-way LDS read conflicts, 1.7e7 cy):
// LDS slot [row*64 + p*16] holds global k-chunk (p + (row>>1)) & 3. Staging
// global chunk for thread t: ((t&3) + ((srow>>1)&3)) & 3 — same 64B segment
// per quad, permuted internally (coalescing invariant). Fragment read lane l
// (rho=l&15, kappa=l>>4) uses p = (kappa - (rho>>1)) & 3; every 8-lane phase
// then hits all 8 bank-quads exactly once (hand-verified) -> 0 conflicts.
//
// XCD patch swizzle kept (FETCH 156->115 MB in round 3).
// ---------------------------------------------------------------------------
__global__ __launch_bounds__(256) void gemm_i8_dq(const int8_t* __restrict__ A,
                                                  const int8_t* __restrict__ W,
                                                  const float* __restrict__ sx,
                                                  const float* __restrict__ sw,
                                                  const float* __restrict__ bias,
                                                  float* __restrict__ out) {
    __shared__ int8_t sA[128 * 64];   // 8 KB, row-major 64B rows
    __shared__ int8_t sB[128 * 64];   // 8 KB

    const int t    = threadIdx.x;
    const int lane = t & 63;
    const int w    = t >> 6;
    const int wm   = w >> 1;          // 0..1
    const int wn   = w & 1;           // 0..1

    // XCD-patch swizzle (bijective remap of 2048 block ids)
    const int flat = blockIdx.y * 32 + blockIdx.x;
    const int xcd  = flat & 7;
    const int idx  = flat >> 3;                    // 0..255
    const int bn   = (xcd & 3) * 8 + (idx & 7);    // 0..31
    const int bm   = (xcd >> 2) * 32 + (idx >> 3); // 0..63

    // ---- staging addresses (4 issues/thread per K-tile) ----
    const int srow   = t >> 2;                         // 0..63
    const int rot    = (srow >> 1) & 3;
    const int gchunk = ((t & 3) + rot) & 3;            // rotated chunk
    const int scol   = gchunk * 16;
    const int8_t* gA0 = A + (size_t)(bm * 128 + srow) * K_DIM + scol;
    const int8_t* gA1 = A + (size_t)(bm * 128 + 64 + srow) * K_DIM + scol;
    const int8_t* gB0 = W + (size_t)(bn * 128 + srow) * K_DIM + scol;
    const int8_t* gB1 = W + (size_t)(bn * 128 + 64 + srow) * K_DIM + scol;
    int8_t* lA0 = &sA[t * 16];
    int8_t* lA1 = &sA[4096 + t * 16];
    int8_t* lB0 = &sB[t * 16];
    int8_t* lB1 = &sB[4096 + t * 16];

    // ---- fragment read addresses ----
    // lane holds X[row = frow][k-chunk kappa = lane>>4]; physical slot
    // p = (kappa - (rho>>1)) & 3 with rho = lane&15 (rot indep. of i, wm/wn).
    const int rho  = lane & 15;
    const int p16  = (((lane >> 4) - (rho >> 1)) & 3) * 16;
    const int aoff = (wm * 64 + rho) * 64 + p16;
    const int boff = (wn * 64 + rho) * 64 + p16;

    v4i acc[4][4];
    const v4i vzero = {0, 0, 0, 0};
#pragma unroll
    for (int mi = 0; mi < 4; mi++)
#pragma unroll
        for (int ni = 0; ni < 4; ni++) acc[mi][ni] = vzero;

    for (int kt = 0; kt < K_DIM; kt += 64) {
        __syncthreads();              // previous tile's ds_reads done
        gload_lds16(gA0 + kt, lA0);
        gload_lds16(gA1 + kt, lA1);
        gload_lds16(gB0 + kt, lB0);
        gload_lds16(gB1 + kt, lB1);
        __syncthreads();              // staging complete

        v4i af[4], bf[4];
#pragma unroll
        for (int i = 0; i < 4; i++) {
            af[i] = *(const v4i*)(&sA[aoff + i * 1024]);   // i*16 rows * 64B
            bf[i] = *(const v4i*)(&sB[boff + i * 1024]);
        }
#pragma unroll
        for (int mi = 0; mi < 4; mi++)
#pragma unroll
            for (int ni = 0; ni < 4; ni++)
                acc[mi][ni] = __builtin_amdgcn_mfma_i32_16x16x64_i8(
                    af[mi], bf[ni], acc[mi][ni], 0, 0, 0);
    }

    // ---- epilogue: C/D 16x16 layout: col = lane&15, row = (lane>>4)*4 + r ----
    const float DIVF = (float)(1.0 / (127.0 * 127.0));
    const int col0 = bn * 128 + wn * 64 + (lane & 15);
    const int row0 = bm * 128 + wm * 64 + (lane >> 4) * 4;

    float swv[4], bv[4];
#pragma unroll
    for (int ni = 0; ni < 4; ni++) {
        swv[ni] = sw[col0 + ni * 16];
        bv[ni]  = bias[col0 + ni * 16];
    }

#pragma unroll
    for (int mi = 0; mi < 4; mi++) {
#pragma unroll
        for (int r = 0; r < 4; r++) {
            const int row = row0 + mi * 16 + r;
            const float xs = sx[row];
#pragma unroll
            for (int ni = 0; ni < 4; ni++) {
                // numpy op order: ((acc_f * DIV) * sx) * sw + bias, no fma
                float v = __fmul_rn((float)acc[mi][ni][r], DIVF);
                v = __fmul_rn(v, xs);
                v = __fmul_rn(v, swv[ni]);
                v = __fadd_rn(v, bv[ni]);
                out[(size_t)row * N_DIM + col0 + ni * 16] = __half2float(__float2half(v));
            }
        }
    }
}

extern "C" void kernel_launch(void* const* d_in, const int* in_sizes, int n_in,
                              void* d_out, int out_size, void* d_ws, size_t ws_size,
                              hipStream_t stream) {
    const int*   x_i32 = (const int*)d_in[0];      // [M,K] int (widened int8)
    const float* sx    = (const float*)d_in[1];    // [M] f32
    const int*   w_i32 = (const int*)d_in[2];      // [N,K] int (widened int8)
    const float* sw    = (const float*)d_in[3];    // [N] f32
    const float* bias  = (const float*)d_in[4];    // [N] f32 (widened fp16)
    float* out = (float*)d_out;                    // [M,N] f32 (widened fp16)

    uint8_t* xb = (uint8_t*)d_ws;                          // 32 MB packed x
    uint8_t* wb = (uint8_t*)d_ws + (size_t)M_DIM * K_DIM;  // 16 MB packed w

    const int nx4 = (M_DIM * K_DIM) / 4;
    const int nw4 = (N_DIM * K_DIM) / 4;
    pack_i32_to_i8<<<(nx4 + 255) / 256, 256, 0, stream>>>(x_i32, (uint32_t*)xb, nx4);
    pack_i32_to_i8<<<(nw4 + 255) / 256, 256, 0, stream>>>(w_i32, (uint32_t*)wb, nw4);

    dim3 grid(N_DIM / 128, M_DIM / 128);  // (32, 64)
    gemm_i8_dq<<<grid, 256, 0, stream>>>((const int8_t*)xb, (const int8_t*)wb,
                                         sx, sw, bias, out);
}